// Round 4
// baseline (2780.862 us; speedup 1.0000x reference)
//
#include <hip/hip_runtime.h>

#define NNODES 100000
#define NEDGES 200000
#define NB     2048
#define DIM    256
#define NLAYERS 5
#define ROWS   32   // rows per fused-MLP block; 100000 % 32 == 0 -> no tail masking

typedef __bf16 bf16x8 __attribute__((ext_vector_type(8)));
typedef float  f32x4  __attribute__((ext_vector_type(4)));

__device__ __forceinline__ float bf2f(unsigned short u) {
    union { unsigned u; float f; } v; v.u = ((unsigned)u) << 16; return v.f;
}
__device__ __forceinline__ unsigned short f2bf(float f) {
    union { float f; unsigned u; } v; v.f = f;
    unsigned r = v.u + 0x7fff + ((v.u >> 16) & 1);   // RNE (finite values only)
    return (unsigned short)(r >> 16);
}

// h-storage abstraction: fp32 path or bf16 path depending on ws_size
__device__ __forceinline__ float loadH(const float* p, size_t i) { return p[i]; }
__device__ __forceinline__ float loadH(const unsigned short* p, size_t i) { return bf2f(p[i]); }
__device__ __forceinline__ void  storeH(float* p, size_t i, float v) { p[i] = v; }
__device__ __forceinline__ void  storeH(unsigned short* p, size_t i, float v) { p[i] = f2bf(v); }

__global__ void zero_f32(float* __restrict__ p, int n) {
    int i = blockIdx.x * 256 + threadIdx.x;
    if (i < n) p[i] = 0.f;
}

// ---- transpose+convert weights: W (L x K x Nw) fp32 -> Wt (L x Nw x K) bf16 ----
__global__ void transpose_w(const float* __restrict__ W,
                            unsigned short* __restrict__ Wt, int K, int Nw) {
    int l = blockIdx.y;
    int t = blockIdx.x * 256 + threadIdx.x;
    int total = K * Nw;
    if (t >= total) return;
    int k = t / Nw, n = t % Nw;
    Wt[(size_t)l * total + (size_t)n * K + k] = f2bf(W[(size_t)l * total + t]);
}

// ---- h = x_emb1[x0] + x_emb2[x1] ----
template <typename HT>
__global__ void node_init(const int* __restrict__ x,
                          const float* __restrict__ xe1,
                          const float* __restrict__ xe2,
                          HT* __restrict__ h) {
    int i = blockIdx.x, d = threadIdx.x;
    int i0 = x[2 * i], i1 = x[2 * i + 1];
    storeH(h, (size_t)i * DIM + d, xe1[i0 * DIM + d] + xe2[i1 * DIM + d]);
}

// ---- agg = h + self_e ----
template <typename HT>
__global__ void agg_init(const HT* __restrict__ h,
                         const float* __restrict__ ee1,
                         const float* __restrict__ ee2,
                         float* __restrict__ agg, int l) {
    size_t idx = (size_t)blockIdx.x * 256 + threadIdx.x;
    int d = (int)(idx & (DIM - 1));
    float se = ee1[(l * 5 + 4) * DIM + d] + ee2[(l * 3 + 0) * DIM + d];
    agg[idx] = loadH(h, idx) + se;
}

// ---- agg[dst] += h[src] + e  (atomic fp32) ----
template <typename HT>
__global__ void edge_scatter(const int* __restrict__ ei, const int* __restrict__ ea,
                             const float* __restrict__ ee1,
                             const float* __restrict__ ee2,
                             const HT* __restrict__ h, float* __restrict__ agg, int l) {
    int j = blockIdx.x, d = threadIdx.x;
    int src = ei[j], dst = ei[NEDGES + j];
    int bt = ea[2 * j], bd = ea[2 * j + 1];
    float e = ee1[(l * 5 + bt) * DIM + d] + ee2[(l * 3 + bd) * DIM + d];
    atomicAdd(&agg[(size_t)dst * DIM + d], loadH(h, (size_t)src * DIM + d) + e);
}

// ---- fused MLP: z = relu(z @ W1 + b1) @ W2 + b2, in place over z (agg) ----
// 32 rows per block, 4 waves. Stage 1: wave w -> t cols [w*128,+128); 2x8 mfma tiles.
// Stage 2: wave w -> z cols [w*64,+64); 2x4 mfma tiles. Weights streamed from global (L2).
__global__ __launch_bounds__(256) void mlp_fused(float* __restrict__ z,
                                                 const unsigned short* __restrict__ Wt1,
                                                 const float* __restrict__ b1,
                                                 const unsigned short* __restrict__ Wt2,
                                                 const float* __restrict__ b2) {
    __shared__ unsigned short As[ROWS * (DIM + 8)];        // 32 x 264 bf16, 16.9 KB
    __shared__ unsigned short Ts[ROWS * (2 * DIM + 8)];    // 32 x 520 bf16, 33.3 KB

    const int rowBase = blockIdx.x * ROWS;
    const int tid = threadIdx.x;
    const int lane = tid & 63, w = tid >> 6;
    const int lrow = lane & 15, lq = lane >> 4;

    // stage A: 32x256 fp32 -> bf16 LDS (2048 float4, 8 per thread)
    #pragma unroll
    for (int c = tid; c < ROWS * DIM / 4; c += 256) {
        int r = c >> 6, cc = c & 63;
        float4 v = *(const float4*)&z[(size_t)(rowBase + r) * DIM + cc * 4];
        ushort4 p; p.x = f2bf(v.x); p.y = f2bf(v.y); p.z = f2bf(v.z); p.w = f2bf(v.w);
        *(ushort4*)&As[r * (DIM + 8) + cc * 4] = p;
    }
    __syncthreads();

    // stage 1: t = relu(A @ W1 + b1) -> Ts
    {
        f32x4 acc[2][8]{};
        #pragma unroll
        for (int kk = 0; kk < DIM / 32; ++kk) {
            const int kc = kk * 32 + lq * 8;
            bf16x8 a[2], b[8];
            #pragma unroll
            for (int mi = 0; mi < 2; ++mi)
                a[mi] = *(const bf16x8*)&As[(mi * 16 + lrow) * (DIM + 8) + kc];
            #pragma unroll
            for (int ni = 0; ni < 8; ++ni)
                b[ni] = *(const bf16x8*)&Wt1[(size_t)(w * 128 + ni * 16 + lrow) * DIM + kc];
            #pragma unroll
            for (int mi = 0; mi < 2; ++mi)
                #pragma unroll
                for (int ni = 0; ni < 8; ++ni)
                    acc[mi][ni] = __builtin_amdgcn_mfma_f32_16x16x32_bf16(a[mi], b[ni], acc[mi][ni], 0, 0, 0);
        }
        #pragma unroll
        for (int ni = 0; ni < 8; ++ni) {
            int col = w * 128 + ni * 16 + lrow;
            float bv = b1[col];
            #pragma unroll
            for (int mi = 0; mi < 2; ++mi)
                #pragma unroll
                for (int r = 0; r < 4; ++r)
                    Ts[(mi * 16 + lq * 4 + r) * (2 * DIM + 8) + col] =
                        f2bf(fmaxf(acc[mi][ni][r] + bv, 0.f));
        }
    }
    __syncthreads();

    // stage 2: z = T @ W2 + b2 (in place)
    {
        f32x4 acc[2][4]{};
        #pragma unroll
        for (int kk = 0; kk < 2 * DIM / 32; ++kk) {
            const int kc = kk * 32 + lq * 8;
            bf16x8 a[2], b[4];
            #pragma unroll
            for (int mi = 0; mi < 2; ++mi)
                a[mi] = *(const bf16x8*)&Ts[(mi * 16 + lrow) * (2 * DIM + 8) + kc];
            #pragma unroll
            for (int ni = 0; ni < 4; ++ni)
                b[ni] = *(const bf16x8*)&Wt2[(size_t)(w * 64 + ni * 16 + lrow) * (2 * DIM) + kc];
            #pragma unroll
            for (int mi = 0; mi < 2; ++mi)
                #pragma unroll
                for (int ni = 0; ni < 4; ++ni)
                    acc[mi][ni] = __builtin_amdgcn_mfma_f32_16x16x32_bf16(a[mi], b[ni], acc[mi][ni], 0, 0, 0);
        }
        #pragma unroll
        for (int ni = 0; ni < 4; ++ni) {
            int col = w * 64 + ni * 16 + lrow;
            float bv = b2[col];
            #pragma unroll
            for (int mi = 0; mi < 2; ++mi)
                #pragma unroll
                for (int r = 0; r < 4; ++r)
                    z[(size_t)(rowBase + mi * 16 + lq * 4 + r) * DIM + col] = acc[mi][ni][r] + bv;
        }
    }
}

// ---- per-column sums / sumsq over N rows ----
__global__ void col_stats(const float* __restrict__ z, float* __restrict__ stats) {
    int d = threadIdx.x;
    float s = 0.f, q = 0.f;
    for (int i = blockIdx.x; i < NNODES; i += gridDim.x) {
        float v = z[(size_t)i * DIM + d];
        s += v; q += v * v;
    }
    atomicAdd(&stats[d], s);
    atomicAdd(&stats[DIM + d], q);
}

__global__ void bn_finalize(const float* __restrict__ stats,
                            const float* __restrict__ g,
                            const float* __restrict__ b,
                            float* __restrict__ ac, int l) {
    int d = threadIdx.x;
    float mu = stats[d] / (float)NNODES;
    float var = stats[DIM + d] / (float)NNODES - mu * mu;
    float inv = rsqrtf(var + 1e-5f);
    float a = g[l * DIM + d] * inv;
    ac[d] = a;
    ac[DIM + d] = b[l * DIM + d] - mu * a;
}

template <typename HT>
__global__ void bn_apply(const float* __restrict__ z, const float* __restrict__ ac,
                         HT* __restrict__ h) {
    size_t idx = (size_t)blockIdx.x * 256 + threadIdx.x;
    int d = (int)(idx & (DIM - 1));
    float v = z[idx] * ac[d] + ac[DIM + d];
    storeH(h, idx, fmaxf(v, 0.f));
}

__global__ void batch_count(const int* __restrict__ batch, float* __restrict__ cnt) {
    int i = blockIdx.x * 256 + threadIdx.x;
    if (i < NNODES) atomicAdd(&cnt[batch[i]], 1.0f);
}

template <typename HT>
__global__ void pool_sum(const int* __restrict__ batch, const HT* __restrict__ h,
                         float* __restrict__ pooled) {
    int i = blockIdx.x, d = threadIdx.x;
    atomicAdd(&pooled[(size_t)batch[i] * DIM + d], loadH(h, (size_t)i * DIM + d));
}

// ---- out = softplus(pooled/cnt @ Wo1 + bo1) @ Wo2 + bo2, out is fp32 ----
__global__ __launch_bounds__(128) void head_mlp(const float* __restrict__ pooled,
                                                const float* __restrict__ cnt,
                                                const float* __restrict__ Wo1,
                                                const float* __restrict__ bo1,
                                                const float* __restrict__ Wo2,
                                                const float* __restrict__ bo2,
                                                float* __restrict__ out) {
    __shared__ float p[DIM];
    __shared__ float r0[128], r1[128];
    int g = blockIdx.x, j = threadIdx.x;
    float inv = 1.0f / fmaxf(cnt[g], 1.0f);
    for (int k = j; k < DIM; k += 128) p[k] = pooled[(size_t)g * DIM + k] * inv;
    __syncthreads();
    float acc = bo1[j];
    for (int k = 0; k < DIM; ++k) acc += p[k] * Wo1[k * 128 + j];
    float sp = (acc > 20.f) ? acc : log1pf(expf(acc));
    r0[j] = sp * Wo2[j * 2 + 0];
    r1[j] = sp * Wo2[j * 2 + 1];
    __syncthreads();
    for (int s = 64; s > 0; s >>= 1) {
        if (j < s) { r0[j] += r0[j + s]; r1[j] += r1[j + s]; }
        __syncthreads();
    }
    if (j == 0) {
        out[g * 2 + 0] = r0[0] + bo2[0];
        out[g * 2 + 1] = r1[0] + bo2[1];
    }
}

template <typename HT>
static void pipeline(void* const* d_in, float* out, char* ws, hipStream_t stream) {
    const int* x     = (const int*)d_in[0];
    const int* ei    = (const int*)d_in[1];
    const int* ea    = (const int*)d_in[2];
    const int* batch = (const int*)d_in[3];
    const float* xe1 = (const float*)d_in[4];
    const float* xe2 = (const float*)d_in[5];
    const float* ee1 = (const float*)d_in[6];
    const float* ee2 = (const float*)d_in[7];
    const float* W1  = (const float*)d_in[8];
    const float* b1  = (const float*)d_in[9];
    const float* W2  = (const float*)d_in[10];
    const float* b2  = (const float*)d_in[11];
    const float* bng = (const float*)d_in[12];
    const float* bnb = (const float*)d_in[13];
    const float* Wo1 = (const float*)d_in[14];
    const float* bo1 = (const float*)d_in[15];
    const float* Wo2 = (const float*)d_in[16];
    const float* bo2 = (const float*)d_in[17];

    size_t off = 0;
    auto alloc = [&](size_t bytes) { void* p = ws + off; off += (bytes + 255) & ~255ull; return p; };
    float* z            = (float*)alloc((size_t)NNODES * DIM * 4);           // agg & z
    HT* h               = (HT*)alloc((size_t)NNODES * DIM * sizeof(HT));
    unsigned short* Wt1 = (unsigned short*)alloc((size_t)NLAYERS * DIM * 2 * DIM * 2);
    unsigned short* Wt2 = (unsigned short*)alloc((size_t)NLAYERS * DIM * 2 * DIM * 2);
    float* stats        = (float*)alloc(2 * DIM * 4);
    float* ac           = (float*)alloc(2 * DIM * 4);
    float* pooled       = (float*)alloc((size_t)NB * DIM * 4);
    float* cnt          = (float*)alloc((size_t)NB * 4);

    const int WTOT = DIM * 2 * DIM;  // 131072 elems / layer

    transpose_w<<<dim3((WTOT + 255) / 256, NLAYERS), 256, 0, stream>>>(W1, Wt1, DIM, 2 * DIM);
    transpose_w<<<dim3((WTOT + 255) / 256, NLAYERS), 256, 0, stream>>>(W2, Wt2, 2 * DIM, DIM);
    node_init<HT><<<NNODES, DIM, 0, stream>>>(x, xe1, xe2, h);

    for (int l = 0; l < NLAYERS; ++l) {
        agg_init<HT><<<(NNODES * DIM) / 256, 256, 0, stream>>>(h, ee1, ee2, z, l);
        edge_scatter<HT><<<NEDGES, DIM, 0, stream>>>(ei, ea, ee1, ee2, h, z, l);
        mlp_fused<<<NNODES / ROWS, 256, 0, stream>>>(z, Wt1 + (size_t)l * WTOT, b1 + l * 2 * DIM,
                                                     Wt2 + (size_t)l * WTOT, b2 + l * DIM);
        zero_f32<<<2, 256, 0, stream>>>(stats, 2 * DIM);
        col_stats<<<1024, DIM, 0, stream>>>(z, stats);
        bn_finalize<<<1, DIM, 0, stream>>>(stats, bng, bnb, ac, l);
        bn_apply<HT><<<(NNODES * DIM) / 256, 256, 0, stream>>>(z, ac, h);
    }

    zero_f32<<<(NB * DIM) / 256, 256, 0, stream>>>(pooled, NB * DIM);
    zero_f32<<<NB / 256, 256, 0, stream>>>(cnt, NB);
    batch_count<<<(NNODES + 255) / 256, 256, 0, stream>>>(batch, cnt);
    pool_sum<HT><<<NNODES, DIM, 0, stream>>>(batch, h, pooled);
    head_mlp<<<NB, 128, 0, stream>>>(pooled, cnt, Wo1, bo1, Wo2, bo2, out);
}

extern "C" void kernel_launch(void* const* d_in, const int* in_sizes, int n_in,
                              void* d_out, int out_size, void* d_ws, size_t ws_size,
                              hipStream_t stream) {
    (void)in_sizes; (void)n_in; (void)out_size;
    // workspace needs: z 102.4MB + h (fp32 102.4MB | bf16 51.2MB) + ~4.8MB fixed
    const size_t NEED_F32 = 210u * 1000u * 1000u;
    const size_t NEED_B16 = 159u * 1000u * 1000u;
    if (ws_size >= NEED_F32)
        pipeline<float>(d_in, (float*)d_out, (char*)d_ws, stream);
    else if (ws_size >= NEED_B16)
        pipeline<unsigned short>(d_in, (float*)d_out, (char*)d_ws, stream);
    // else: insufficient scratch — launch nothing (visible absmax failure, no fault)
}

// Round 5
// 1782.187 us; speedup vs baseline: 1.5604x; 1.5604x over previous
//
#include <hip/hip_runtime.h>

#define NNODES 100000
#define NEDGES 200000
#define NB     2048
#define DIM    256
#define NLAYERS 5
#define NSB    98   // ceil(100000/1024) scan blocks

typedef __bf16 bf16x8 __attribute__((ext_vector_type(8)));
typedef float  f32x4  __attribute__((ext_vector_type(4)));

__device__ __forceinline__ float bf2f(unsigned short u) {
    union { unsigned u; float f; } v; v.u = ((unsigned)u) << 16; return v.f;
}
__device__ __forceinline__ unsigned short f2bf(float f) {
    union { float f; unsigned u; } v; v.f = f;
    unsigned r = v.u + 0x7fff + ((v.u >> 16) & 1);   // RNE (finite values only)
    return (unsigned short)(r >> 16);
}

// z-storage abstraction (fp32 or bf16 depending on ws_size)
__device__ __forceinline__ void storeH(float* p, size_t i, float v) { p[i] = v; }
__device__ __forceinline__ void storeH(unsigned short* p, size_t i, float v) { p[i] = f2bf(v); }
__device__ __forceinline__ float4 loadZ4(const float* z, size_t row, int ch) {
    return *(const float4*)&z[row * DIM + ch];
}
__device__ __forceinline__ float4 loadZ4(const unsigned short* z, size_t row, int ch) {
    ushort4 u = *(const ushort4*)&z[row * DIM + ch];
    float4 r; r.x = bf2f(u.x); r.y = bf2f(u.y); r.z = bf2f(u.z); r.w = bf2f(u.w); return r;
}

__global__ void zero_f32(float* __restrict__ p, int n) {
    int i = blockIdx.x * 256 + threadIdx.x;
    if (i < n) p[i] = 0.f;
}
__global__ void zero_i32(int* __restrict__ p, int n) {
    int i = blockIdx.x * 256 + threadIdx.x;
    if (i < n) p[i] = 0;
}

// ---- transpose+convert weights: W (L x K x Nw) fp32 -> Wt (L x Nw x K) bf16 ----
__global__ void transpose_w(const float* __restrict__ W,
                            unsigned short* __restrict__ Wt, int K, int Nw) {
    int l = blockIdx.y;
    int t = blockIdx.x * 256 + threadIdx.x;
    int total = K * Nw;
    if (t >= total) return;
    int k = t / Nw, n = t % Nw;
    Wt[(size_t)l * total + (size_t)n * K + k] = f2bf(W[(size_t)l * total + t]);
}

// ---- edge-embedding table: etab[l][bt*3+bd][d] = ee1[l][bt][d] + ee2[l][bd][d] ----
__global__ void build_etab(const float* __restrict__ ee1, const float* __restrict__ ee2,
                           float* __restrict__ etab) {
    int l = blockIdx.y, c = blockIdx.x, d = threadIdx.x;   // c in [0,15)
    etab[((size_t)l * 15 + c) * DIM + d] =
        ee1[((size_t)l * 5 + c / 3) * DIM + d] + ee2[((size_t)l * 3 + c % 3) * DIM + d];
}

// ---- h0 = x_emb1[x0] + x_emb2[x1] -> z ----
template <typename HT>
__global__ void node_init(const int* __restrict__ x,
                          const float* __restrict__ xe1,
                          const float* __restrict__ xe2,
                          HT* __restrict__ z) {
    int i = blockIdx.x, d = threadIdx.x;
    int i0 = x[2 * i], i1 = x[2 * i + 1];
    storeH(z, (size_t)i * DIM + d, xe1[i0 * DIM + d] + xe2[i1 * DIM + d]);
}

// ---- CSR build ----
__global__ void csr_hist(const int* __restrict__ ei, int* __restrict__ deg) {
    int j = blockIdx.x * 256 + threadIdx.x;
    if (j < NEDGES) atomicAdd(&deg[ei[NEDGES + j]], 1);
}
__global__ __launch_bounds__(1024) void scan_blk(const int* __restrict__ deg,
                                                 int* __restrict__ rowptr,
                                                 int* __restrict__ bsum) {
    __shared__ int s[1024];
    int b = blockIdx.x, t = threadIdx.x, i = b * 1024 + t;
    s[t] = (i < NNODES) ? deg[i] : 0;
    __syncthreads();
    #pragma unroll
    for (int off = 1; off < 1024; off <<= 1) {
        int u = (t >= off) ? s[t - off] : 0;
        __syncthreads();
        s[t] += u;
        __syncthreads();
    }
    if (i < NNODES) rowptr[i + 1] = s[t];
    if (t == 1023) bsum[b] = s[1023];
}
__global__ void scan_partials(int* __restrict__ bsum) {
    if (threadIdx.x == 0) {
        int acc = 0;
        for (int k = 0; k < NSB; ++k) { acc += bsum[k]; bsum[k] = acc; }
    }
}
__global__ void scan_add(int* __restrict__ rowptr, const int* __restrict__ bsum) {
    int b = blockIdx.x, t = threadIdx.x, i = b * 1024 + t;
    if (b > 0 && i < NNODES) rowptr[i + 1] += bsum[b - 1];
    if (b == 0 && t == 0) rowptr[0] = 0;
}
__global__ void csr_fill(const int* __restrict__ ei, const int* __restrict__ ea,
                         const int* __restrict__ rowptr, int* __restrict__ cur,
                         int* __restrict__ esrc, int* __restrict__ eattr) {
    int j = blockIdx.x * 256 + threadIdx.x;
    if (j >= NEDGES) return;
    int d = ei[NEDGES + j];
    int pos = atomicAdd(&cur[d], 1);
    int slot = rowptr[d] + pos;
    esrc[slot] = ei[j];
    eattr[slot] = ea[2 * j] * 3 + ea[2 * j + 1];
}

// ---- gather: agg[i] = sum_in(h(src)+e) + h(i) + self_e, h(x)=applyBN? relu(z*a+c) : z ----
// wave per node, lane handles 4 channels; agg written bf16
template <typename HT>
__global__ __launch_bounds__(256) void gather_csr(const HT* __restrict__ z,
                                                  const float* __restrict__ acv,
                                                  const float* __restrict__ etab_l,
                                                  const int* __restrict__ rowptr,
                                                  const int* __restrict__ esrc,
                                                  const int* __restrict__ eattr,
                                                  unsigned short* __restrict__ agg,
                                                  int applyBN) {
    int i = blockIdx.x * 4 + (threadIdx.x >> 6);
    int lane = threadIdx.x & 63, ch = lane * 4;
    float4 a4 = make_float4(1.f, 1.f, 1.f, 1.f), c4 = make_float4(0.f, 0.f, 0.f, 0.f);
    if (applyBN) { a4 = *(const float4*)&acv[ch]; c4 = *(const float4*)&acv[DIM + ch]; }

    float4 hv = loadZ4(z, (size_t)i, ch);
    if (applyBN) {
        hv.x = fmaxf(hv.x * a4.x + c4.x, 0.f); hv.y = fmaxf(hv.y * a4.y + c4.y, 0.f);
        hv.z = fmaxf(hv.z * a4.z + c4.z, 0.f); hv.w = fmaxf(hv.w * a4.w + c4.w, 0.f);
    }
    float4 se = *(const float4*)&etab_l[12 * DIM + ch];   // (bt=4,bd=0)
    float4 acc = make_float4(hv.x + se.x, hv.y + se.y, hv.z + se.z, hv.w + se.w);

    int r0 = rowptr[i], r1 = rowptr[i + 1];
    for (int e = r0; e < r1; ++e) {
        int s = esrc[e], cb = eattr[e];
        float4 h = loadZ4(z, (size_t)s, ch);
        if (applyBN) {
            h.x = fmaxf(h.x * a4.x + c4.x, 0.f); h.y = fmaxf(h.y * a4.y + c4.y, 0.f);
            h.z = fmaxf(h.z * a4.z + c4.z, 0.f); h.w = fmaxf(h.w * a4.w + c4.w, 0.f);
        }
        float4 ev = *(const float4*)&etab_l[cb * DIM + ch];
        acc.x += h.x + ev.x; acc.y += h.y + ev.y; acc.z += h.z + ev.z; acc.w += h.w + ev.w;
    }
    ushort4 o; o.x = f2bf(acc.x); o.y = f2bf(acc.y); o.z = f2bf(acc.z); o.w = f2bf(acc.w);
    *(ushort4*)&agg[(size_t)i * DIM + ch] = o;
}

// ---- fused MLP: z = relu(agg @ W1 + b1) @ W2 + b2, with col sum/sumsq in epilogue ----
// 64 rows/block, 8 waves. Stage1: wave w -> cols [w*64,+64) of t (4 n-tiles), A direct
// from global agg (8x intra-block L1 reuse). Stage2: wave w -> cols [w*32,+32) of z.
template <typename HT>
__global__ __launch_bounds__(512, 4) void mlp64(const unsigned short* __restrict__ agg,
                                                const unsigned short* __restrict__ Wt1,
                                                const float* __restrict__ b1,
                                                const unsigned short* __restrict__ Wt2,
                                                const float* __restrict__ b2,
                                                HT* __restrict__ z,
                                                float* __restrict__ stats) {
    __shared__ unsigned short Ts[64 * 520];   // 64 x (512+8) bf16, 66.6 KB

    const int rowBase = blockIdx.x * 64;
    const int tid = threadIdx.x;
    const int lane = tid & 63, w = tid >> 6;
    const int lrow = lane & 15, lq = lane >> 4;

    // stage 1: t = relu(agg @ W1 + b1) -> Ts
    {
        f32x4 acc[4][4]{};
        #pragma unroll
        for (int kk = 0; kk < DIM / 32; ++kk) {
            const int kc = kk * 32 + lq * 8;
            bf16x8 a[4], b[4];
            #pragma unroll
            for (int mi = 0; mi < 4; ++mi) {
                int row = rowBase + mi * 16 + lrow; if (row >= NNODES) row = NNODES - 1;
                a[mi] = *(const bf16x8*)&agg[(size_t)row * DIM + kc];
            }
            #pragma unroll
            for (int ni = 0; ni < 4; ++ni)
                b[ni] = *(const bf16x8*)&Wt1[(size_t)(w * 64 + ni * 16 + lrow) * DIM + kc];
            #pragma unroll
            for (int mi = 0; mi < 4; ++mi)
                #pragma unroll
                for (int ni = 0; ni < 4; ++ni)
                    acc[mi][ni] = __builtin_amdgcn_mfma_f32_16x16x32_bf16(a[mi], b[ni], acc[mi][ni], 0, 0, 0);
        }
        #pragma unroll
        for (int ni = 0; ni < 4; ++ni) {
            int col = w * 64 + ni * 16 + lrow;
            float bv = b1[col];
            #pragma unroll
            for (int mi = 0; mi < 4; ++mi)
                #pragma unroll
                for (int r = 0; r < 4; ++r)
                    Ts[(mi * 16 + lq * 4 + r) * 520 + col] = f2bf(fmaxf(acc[mi][ni][r] + bv, 0.f));
        }
    }
    __syncthreads();

    // stage 2: z = Ts @ W2 + b2 ; per-column sum/sumsq partials -> stats
    {
        f32x4 acc[4][2]{};
        #pragma unroll
        for (int kk = 0; kk < 2 * DIM / 32; ++kk) {
            const int kc = kk * 32 + lq * 8;
            bf16x8 a[4], b[2];
            #pragma unroll
            for (int mi = 0; mi < 4; ++mi)
                a[mi] = *(const bf16x8*)&Ts[(mi * 16 + lrow) * 520 + kc];
            #pragma unroll
            for (int ni = 0; ni < 2; ++ni)
                b[ni] = *(const bf16x8*)&Wt2[(size_t)(w * 32 + ni * 16 + lrow) * (2 * DIM) + kc];
            #pragma unroll
            for (int mi = 0; mi < 4; ++mi)
                #pragma unroll
                for (int ni = 0; ni < 2; ++ni)
                    acc[mi][ni] = __builtin_amdgcn_mfma_f32_16x16x32_bf16(a[mi], b[ni], acc[mi][ni], 0, 0, 0);
        }
        #pragma unroll
        for (int ni = 0; ni < 2; ++ni) {
            int col = w * 32 + ni * 16 + lrow;
            float bv = b2[col];
            float s = 0.f, q = 0.f;
            #pragma unroll
            for (int mi = 0; mi < 4; ++mi)
                #pragma unroll
                for (int r = 0; r < 4; ++r) {
                    int row = rowBase + mi * 16 + lq * 4 + r;
                    if (row < NNODES) {
                        float v = acc[mi][ni][r] + bv;
                        storeH(z, (size_t)row * DIM + col, v);
                        s += v; q += v * v;
                    }
                }
            s += __shfl_xor(s, 16); s += __shfl_xor(s, 32);
            q += __shfl_xor(q, 16); q += __shfl_xor(q, 32);
            if (lq == 0) {
                atomicAdd(&stats[col], s);
                atomicAdd(&stats[DIM + col], q);
            }
        }
    }
}

__global__ void bn_finalize(const float* __restrict__ stats,
                            const float* __restrict__ g,
                            const float* __restrict__ b,
                            float* __restrict__ ac, int l) {
    int d = threadIdx.x;
    float mu = stats[d] / (float)NNODES;
    float var = stats[DIM + d] / (float)NNODES - mu * mu;
    float inv = rsqrtf(var + 1e-5f);
    float a = g[l * DIM + d] * inv;
    ac[d] = a;
    ac[DIM + d] = b[l * DIM + d] - mu * a;
}

__global__ void batch_count(const int* __restrict__ batch, float* __restrict__ cnt) {
    int i = blockIdx.x * 256 + threadIdx.x;
    if (i < NNODES) atomicAdd(&cnt[batch[i]], 1.0f);
}

// ---- pooled[g] += relu(z[i]*a+c) ; wave per node ----
template <typename HT>
__global__ __launch_bounds__(256) void pool_gather(const HT* __restrict__ z,
                                                   const float* __restrict__ acv,
                                                   const int* __restrict__ batch,
                                                   float* __restrict__ pooled) {
    int i = blockIdx.x * 4 + (threadIdx.x >> 6);
    int lane = threadIdx.x & 63, ch = lane * 4;
    float4 a4 = *(const float4*)&acv[ch], c4 = *(const float4*)&acv[DIM + ch];
    float4 v = loadZ4(z, (size_t)i, ch);
    v.x = fmaxf(v.x * a4.x + c4.x, 0.f); v.y = fmaxf(v.y * a4.y + c4.y, 0.f);
    v.z = fmaxf(v.z * a4.z + c4.z, 0.f); v.w = fmaxf(v.w * a4.w + c4.w, 0.f);
    int g = batch[i];
    float* dst = &pooled[(size_t)g * DIM + ch];
    atomicAdd(dst + 0, v.x); atomicAdd(dst + 1, v.y);
    atomicAdd(dst + 2, v.z); atomicAdd(dst + 3, v.w);
}

// ---- out = softplus(pooled/cnt @ Wo1 + bo1) @ Wo2 + bo2, fp32 out ----
__global__ __launch_bounds__(128) void head_mlp(const float* __restrict__ pooled,
                                                const float* __restrict__ cnt,
                                                const float* __restrict__ Wo1,
                                                const float* __restrict__ bo1,
                                                const float* __restrict__ Wo2,
                                                const float* __restrict__ bo2,
                                                float* __restrict__ out) {
    __shared__ float p[DIM];
    __shared__ float r0[128], r1[128];
    int g = blockIdx.x, j = threadIdx.x;
    float inv = 1.0f / fmaxf(cnt[g], 1.0f);
    for (int k = j; k < DIM; k += 128) p[k] = pooled[(size_t)g * DIM + k] * inv;
    __syncthreads();
    float acc = bo1[j];
    for (int k = 0; k < DIM; ++k) acc += p[k] * Wo1[k * 128 + j];
    float sp = (acc > 20.f) ? acc : log1pf(expf(acc));
    r0[j] = sp * Wo2[j * 2 + 0];
    r1[j] = sp * Wo2[j * 2 + 1];
    __syncthreads();
    for (int s = 64; s > 0; s >>= 1) {
        if (j < s) { r0[j] += r0[j + s]; r1[j] += r1[j + s]; }
        __syncthreads();
    }
    if (j == 0) {
        out[g * 2 + 0] = r0[0] + bo2[0];
        out[g * 2 + 1] = r1[0] + bo2[1];
    }
}

template <typename HT>
static void pipeline(void* const* d_in, float* out, char* ws, hipStream_t stream) {
    const int* x     = (const int*)d_in[0];
    const int* ei    = (const int*)d_in[1];
    const int* ea    = (const int*)d_in[2];
    const int* batch = (const int*)d_in[3];
    const float* xe1 = (const float*)d_in[4];
    const float* xe2 = (const float*)d_in[5];
    const float* ee1 = (const float*)d_in[6];
    const float* ee2 = (const float*)d_in[7];
    const float* W1  = (const float*)d_in[8];
    const float* b1  = (const float*)d_in[9];
    const float* W2  = (const float*)d_in[10];
    const float* b2  = (const float*)d_in[11];
    const float* bng = (const float*)d_in[12];
    const float* bnb = (const float*)d_in[13];
    const float* Wo1 = (const float*)d_in[14];
    const float* bo1 = (const float*)d_in[15];
    const float* Wo2 = (const float*)d_in[16];
    const float* bo2 = (const float*)d_in[17];

    size_t off = 0;
    auto alloc = [&](size_t bytes) { void* p = ws + off; off += (bytes + 255) & ~255ull; return p; };
    HT* z               = (HT*)alloc((size_t)NNODES * DIM * sizeof(HT));
    unsigned short* agg = (unsigned short*)alloc((size_t)NNODES * DIM * 2);
    unsigned short* Wt1 = (unsigned short*)alloc((size_t)NLAYERS * DIM * 2 * DIM * 2);
    unsigned short* Wt2 = (unsigned short*)alloc((size_t)NLAYERS * DIM * 2 * DIM * 2);
    float* etab         = (float*)alloc((size_t)NLAYERS * 15 * DIM * 4);
    float* stats        = (float*)alloc(2 * DIM * 4);
    float* ac           = (float*)alloc(2 * DIM * 4);
    float* pooled       = (float*)alloc((size_t)NB * DIM * 4);
    float* cnt          = (float*)alloc((size_t)NB * 4);
    int* rowptr         = (int*)alloc((size_t)(NNODES + 1) * 4);
    int* deg            = (int*)alloc((size_t)NNODES * 4);     // also cursor
    int* esrc           = (int*)alloc((size_t)NEDGES * 4);
    int* eattr          = (int*)alloc((size_t)NEDGES * 4);
    int* bsum           = (int*)alloc((size_t)NSB * 4);

    const int WTOT = DIM * 2 * DIM;  // 131072

    // one-time prep
    transpose_w<<<dim3((WTOT + 255) / 256, NLAYERS), 256, 0, stream>>>(W1, Wt1, DIM, 2 * DIM);
    transpose_w<<<dim3((WTOT + 255) / 256, NLAYERS), 256, 0, stream>>>(W2, Wt2, 2 * DIM, DIM);
    build_etab<<<dim3(15, NLAYERS), DIM, 0, stream>>>(ee1, ee2, etab);
    node_init<HT><<<NNODES, DIM, 0, stream>>>(x, xe1, xe2, z);

    // CSR build
    zero_i32<<<(NNODES + 255) / 256, 256, 0, stream>>>(deg, NNODES);
    csr_hist<<<(NEDGES + 255) / 256, 256, 0, stream>>>(ei, deg);
    scan_blk<<<NSB, 1024, 0, stream>>>(deg, rowptr, bsum);
    scan_partials<<<1, 64, 0, stream>>>(bsum);
    scan_add<<<NSB, 1024, 0, stream>>>(rowptr, bsum);
    zero_i32<<<(NNODES + 255) / 256, 256, 0, stream>>>(deg, NNODES);
    csr_fill<<<(NEDGES + 255) / 256, 256, 0, stream>>>(ei, ea, rowptr, deg, esrc, eattr);

    for (int l = 0; l < NLAYERS; ++l) {
        gather_csr<HT><<<NNODES / 4, 256, 0, stream>>>(z, ac, etab + (size_t)l * 15 * DIM,
                                                       rowptr, esrc, eattr, agg, l > 0 ? 1 : 0);
        zero_f32<<<2, 256, 0, stream>>>(stats, 2 * DIM);
        mlp64<HT><<<(NNODES + 63) / 64, 512, 0, stream>>>(agg, Wt1 + (size_t)l * WTOT, b1 + l * 2 * DIM,
                                                          Wt2 + (size_t)l * WTOT, b2 + l * DIM, z, stats);
        bn_finalize<<<1, DIM, 0, stream>>>(stats, bng, bnb, ac, l);
    }

    zero_f32<<<(NB * DIM) / 256, 256, 0, stream>>>(pooled, NB * DIM);
    zero_f32<<<NB / 256, 256, 0, stream>>>(cnt, NB);
    batch_count<<<(NNODES + 255) / 256, 256, 0, stream>>>(batch, cnt);
    pool_gather<HT><<<NNODES / 4, 256, 0, stream>>>(z, ac, batch, pooled);
    head_mlp<<<NB, 128, 0, stream>>>(pooled, cnt, Wo1, bo1, Wo2, bo2, out);
}

extern "C" void kernel_launch(void* const* d_in, const int* in_sizes, int n_in,
                              void* d_out, int out_size, void* d_ws, size_t ws_size,
                              hipStream_t stream) {
    (void)in_sizes; (void)n_in; (void)out_size;
    // layout A (z fp32): ~161 MB ; layout B (z bf16): ~110 MB
    const size_t NEED_A = 161500000ull;
    const size_t NEED_B = 110500000ull;
    if (ws_size >= NEED_A)
        pipeline<float>(d_in, (float*)d_out, (char*)d_ws, stream);
    else if (ws_size >= NEED_B)
        pipeline<unsigned short>(d_in, (float*)d_out, (char*)d_ws, stream);
    // else: insufficient scratch — launch nothing (visible absmax failure, no fault)
}

// Round 6
// 1409.596 us; speedup vs baseline: 1.9728x; 1.2643x over previous
//
#include <hip/hip_runtime.h>

#define NNODES 100000
#define NEDGES 200000
#define NB     2048
#define DIM    256
#define NLAYERS 5
#define NSB    98   // ceil(100000/1024) scan blocks

typedef __bf16 bf16x8 __attribute__((ext_vector_type(8)));
typedef float  f32x4  __attribute__((ext_vector_type(4)));

__device__ __forceinline__ float bf2f(unsigned short u) {
    union { unsigned u; float f; } v; v.u = ((unsigned)u) << 16; return v.f;
}
__device__ __forceinline__ unsigned short f2bf(float f) {
    union { float f; unsigned u; } v; v.f = f;
    unsigned r = v.u + 0x7fff + ((v.u >> 16) & 1);   // RNE (finite values only)
    return (unsigned short)(r >> 16);
}

// z-storage abstraction (fp32 or bf16 depending on ws_size)
__device__ __forceinline__ float loadH(const float* p, size_t i) { return p[i]; }
__device__ __forceinline__ float loadH(const unsigned short* p, size_t i) { return bf2f(p[i]); }
__device__ __forceinline__ void storeH(float* p, size_t i, float v) { p[i] = v; }
__device__ __forceinline__ void storeH(unsigned short* p, size_t i, float v) { p[i] = f2bf(v); }
__device__ __forceinline__ float4 loadZ4(const float* z, size_t row, int ch) {
    return *(const float4*)&z[row * DIM + ch];
}
__device__ __forceinline__ float4 loadZ4(const unsigned short* z, size_t row, int ch) {
    ushort4 u = *(const ushort4*)&z[row * DIM + ch];
    float4 r; r.x = bf2f(u.x); r.y = bf2f(u.y); r.z = bf2f(u.z); r.w = bf2f(u.w); return r;
}

__global__ void zero_f32(float* __restrict__ p, int n) {
    int i = blockIdx.x * 256 + threadIdx.x;
    if (i < n) p[i] = 0.f;
}
__global__ void zero_i32(int* __restrict__ p, int n) {
    int i = blockIdx.x * 256 + threadIdx.x;
    if (i < n) p[i] = 0;
}

// ---- transpose+convert weights: W (L x K x Nw) fp32 -> Wt (L x Nw x K) bf16 ----
__global__ void transpose_w(const float* __restrict__ W,
                            unsigned short* __restrict__ Wt, int K, int Nw) {
    int l = blockIdx.y;
    int t = blockIdx.x * 256 + threadIdx.x;
    int total = K * Nw;
    if (t >= total) return;
    int k = t / Nw, n = t % Nw;
    Wt[(size_t)l * total + (size_t)n * K + k] = f2bf(W[(size_t)l * total + t]);
}

// ---- edge-embedding table: etab[l][bt*3+bd][d] = ee1[l][bt][d] + ee2[l][bd][d] ----
__global__ void build_etab(const float* __restrict__ ee1, const float* __restrict__ ee2,
                           float* __restrict__ etab) {
    int l = blockIdx.y, c = blockIdx.x, d = threadIdx.x;   // c in [0,15)
    etab[((size_t)l * 15 + c) * DIM + d] =
        ee1[((size_t)l * 5 + c / 3) * DIM + d] + ee2[((size_t)l * 3 + c % 3) * DIM + d];
}

// ---- h0 = x_emb1[x0] + x_emb2[x1] -> z ----
template <typename HT>
__global__ void node_init(const int* __restrict__ x,
                          const float* __restrict__ xe1,
                          const float* __restrict__ xe2,
                          HT* __restrict__ z) {
    int i = blockIdx.x, d = threadIdx.x;
    int i0 = x[2 * i], i1 = x[2 * i + 1];
    storeH(z, (size_t)i * DIM + d, xe1[i0 * DIM + d] + xe2[i1 * DIM + d]);
}

// ---- CSR build ----
__global__ void csr_hist(const int* __restrict__ ei, int* __restrict__ deg) {
    int j = blockIdx.x * 256 + threadIdx.x;
    if (j < NEDGES) atomicAdd(&deg[ei[NEDGES + j]], 1);
}
__global__ __launch_bounds__(1024) void scan_blk(const int* __restrict__ deg,
                                                 int* __restrict__ rowptr,
                                                 int* __restrict__ bsum) {
    __shared__ int s[1024];
    int b = blockIdx.x, t = threadIdx.x, i = b * 1024 + t;
    s[t] = (i < NNODES) ? deg[i] : 0;
    __syncthreads();
    #pragma unroll
    for (int off = 1; off < 1024; off <<= 1) {
        int u = (t >= off) ? s[t - off] : 0;
        __syncthreads();
        s[t] += u;
        __syncthreads();
    }
    if (i < NNODES) rowptr[i + 1] = s[t];
    if (t == 1023) bsum[b] = s[1023];
}
__global__ void scan_partials(int* __restrict__ bsum) {
    if (threadIdx.x == 0) {
        int acc = 0;
        for (int k = 0; k < NSB; ++k) { acc += bsum[k]; bsum[k] = acc; }
    }
}
__global__ void scan_add(int* __restrict__ rowptr, const int* __restrict__ bsum) {
    int b = blockIdx.x, t = threadIdx.x, i = b * 1024 + t;
    if (b > 0 && i < NNODES) rowptr[i + 1] += bsum[b - 1];
    if (b == 0 && t == 0) rowptr[0] = 0;
}
__global__ void csr_fill(const int* __restrict__ ei, const int* __restrict__ ea,
                         const int* __restrict__ rowptr, int* __restrict__ cur,
                         int* __restrict__ esrc, int* __restrict__ eattr) {
    int j = blockIdx.x * 256 + threadIdx.x;
    if (j >= NEDGES) return;
    int d = ei[NEDGES + j];
    int pos = atomicAdd(&cur[d], 1);
    int slot = rowptr[d] + pos;
    esrc[slot] = ei[j];
    eattr[slot] = ea[2 * j] * 3 + ea[2 * j + 1];
}

// ---- segment starts: start[g] = lower_bound(batch, g), g in [0, NB] ----
__global__ void seg_starts(const int* __restrict__ batch, int* __restrict__ start) {
    int g = blockIdx.x * 256 + threadIdx.x;
    if (g > NB) return;
    int lo = 0, hi = NNODES;
    while (lo < hi) { int mid = (lo + hi) >> 1; if (batch[mid] < g) lo = mid + 1; else hi = mid; }
    start[g] = lo;
}

// ---- gather: agg[i] = sum_in(h(src)+e) + h(i) + self_e, h(x)=applyBN? relu(z*a+c) : z ----
// wave per node, lane handles 4 channels; agg written bf16
template <typename HT>
__global__ __launch_bounds__(256) void gather_csr(const HT* __restrict__ z,
                                                  const float* __restrict__ acv,
                                                  const float* __restrict__ etab_l,
                                                  const int* __restrict__ rowptr,
                                                  const int* __restrict__ esrc,
                                                  const int* __restrict__ eattr,
                                                  unsigned short* __restrict__ agg,
                                                  int applyBN) {
    int i = blockIdx.x * 4 + (threadIdx.x >> 6);
    int lane = threadIdx.x & 63, ch = lane * 4;
    float4 a4 = make_float4(1.f, 1.f, 1.f, 1.f), c4 = make_float4(0.f, 0.f, 0.f, 0.f);
    if (applyBN) { a4 = *(const float4*)&acv[ch]; c4 = *(const float4*)&acv[DIM + ch]; }

    float4 hv = loadZ4(z, (size_t)i, ch);
    if (applyBN) {
        hv.x = fmaxf(hv.x * a4.x + c4.x, 0.f); hv.y = fmaxf(hv.y * a4.y + c4.y, 0.f);
        hv.z = fmaxf(hv.z * a4.z + c4.z, 0.f); hv.w = fmaxf(hv.w * a4.w + c4.w, 0.f);
    }
    float4 se = *(const float4*)&etab_l[12 * DIM + ch];   // (bt=4,bd=0)
    float4 acc = make_float4(hv.x + se.x, hv.y + se.y, hv.z + se.z, hv.w + se.w);

    int r0 = rowptr[i], r1 = rowptr[i + 1];
    for (int e = r0; e < r1; ++e) {
        int s = esrc[e], cb = eattr[e];
        float4 h = loadZ4(z, (size_t)s, ch);
        if (applyBN) {
            h.x = fmaxf(h.x * a4.x + c4.x, 0.f); h.y = fmaxf(h.y * a4.y + c4.y, 0.f);
            h.z = fmaxf(h.z * a4.z + c4.z, 0.f); h.w = fmaxf(h.w * a4.w + c4.w, 0.f);
        }
        float4 ev = *(const float4*)&etab_l[cb * DIM + ch];
        acc.x += h.x + ev.x; acc.y += h.y + ev.y; acc.z += h.z + ev.z; acc.w += h.w + ev.w;
    }
    ushort4 o; o.x = f2bf(acc.x); o.y = f2bf(acc.y); o.z = f2bf(acc.z); o.w = f2bf(acc.w);
    *(ushort4*)&agg[(size_t)i * DIM + ch] = o;
}

// ---- fused MLP: z = relu(agg @ W1 + b1) @ W2 + b2, with col sum/sumsq in epilogue ----
template <typename HT>
__global__ __launch_bounds__(512, 4) void mlp64(const unsigned short* __restrict__ agg,
                                                const unsigned short* __restrict__ Wt1,
                                                const float* __restrict__ b1,
                                                const unsigned short* __restrict__ Wt2,
                                                const float* __restrict__ b2,
                                                HT* __restrict__ z,
                                                float* __restrict__ stats) {
    __shared__ unsigned short Ts[64 * 520];   // 64 x (512+8) bf16, 66.6 KB

    const int rowBase = blockIdx.x * 64;
    const int tid = threadIdx.x;
    const int lane = tid & 63, w = tid >> 6;
    const int lrow = lane & 15, lq = lane >> 4;

    // stage 1: t = relu(agg @ W1 + b1) -> Ts
    {
        f32x4 acc[4][4]{};
        #pragma unroll
        for (int kk = 0; kk < DIM / 32; ++kk) {
            const int kc = kk * 32 + lq * 8;
            bf16x8 a[4], b[4];
            #pragma unroll
            for (int mi = 0; mi < 4; ++mi) {
                int row = rowBase + mi * 16 + lrow; if (row >= NNODES) row = NNODES - 1;
                a[mi] = *(const bf16x8*)&agg[(size_t)row * DIM + kc];
            }
            #pragma unroll
            for (int ni = 0; ni < 4; ++ni)
                b[ni] = *(const bf16x8*)&Wt1[(size_t)(w * 64 + ni * 16 + lrow) * DIM + kc];
            #pragma unroll
            for (int mi = 0; mi < 4; ++mi)
                #pragma unroll
                for (int ni = 0; ni < 4; ++ni)
                    acc[mi][ni] = __builtin_amdgcn_mfma_f32_16x16x32_bf16(a[mi], b[ni], acc[mi][ni], 0, 0, 0);
        }
        #pragma unroll
        for (int ni = 0; ni < 4; ++ni) {
            int col = w * 64 + ni * 16 + lrow;
            float bv = b1[col];
            #pragma unroll
            for (int mi = 0; mi < 4; ++mi)
                #pragma unroll
                for (int r = 0; r < 4; ++r)
                    Ts[(mi * 16 + lq * 4 + r) * 520 + col] = f2bf(fmaxf(acc[mi][ni][r] + bv, 0.f));
        }
    }
    __syncthreads();

    // stage 2: z = Ts @ W2 + b2 ; per-column sum/sumsq partials -> stats
    {
        f32x4 acc[4][2]{};
        #pragma unroll
        for (int kk = 0; kk < 2 * DIM / 32; ++kk) {
            const int kc = kk * 32 + lq * 8;
            bf16x8 a[4], b[2];
            #pragma unroll
            for (int mi = 0; mi < 4; ++mi)
                a[mi] = *(const bf16x8*)&Ts[(mi * 16 + lrow) * 520 + kc];
            #pragma unroll
            for (int ni = 0; ni < 2; ++ni)
                b[ni] = *(const bf16x8*)&Wt2[(size_t)(w * 32 + ni * 16 + lrow) * (2 * DIM) + kc];
            #pragma unroll
            for (int mi = 0; mi < 4; ++mi)
                #pragma unroll
                for (int ni = 0; ni < 2; ++ni)
                    acc[mi][ni] = __builtin_amdgcn_mfma_f32_16x16x32_bf16(a[mi], b[ni], acc[mi][ni], 0, 0, 0);
        }
        #pragma unroll
        for (int ni = 0; ni < 2; ++ni) {
            int col = w * 32 + ni * 16 + lrow;
            float bv = b2[col];
            float s = 0.f, q = 0.f;
            #pragma unroll
            for (int mi = 0; mi < 4; ++mi)
                #pragma unroll
                for (int r = 0; r < 4; ++r) {
                    int row = rowBase + mi * 16 + lq * 4 + r;
                    if (row < NNODES) {
                        float v = acc[mi][ni][r] + bv;
                        storeH(z, (size_t)row * DIM + col, v);
                        s += v; q += v * v;
                    }
                }
            s += __shfl_xor(s, 16); s += __shfl_xor(s, 32);
            q += __shfl_xor(q, 16); q += __shfl_xor(q, 32);
            if (lq == 0) {
                atomicAdd(&stats[col], s);
                atomicAdd(&stats[DIM + col], q);
            }
        }
    }
}

__global__ void bn_finalize(const float* __restrict__ stats,
                            const float* __restrict__ g,
                            const float* __restrict__ b,
                            float* __restrict__ ac, int l) {
    int d = threadIdx.x;
    float mu = stats[d] / (float)NNODES;
    float var = stats[DIM + d] / (float)NNODES - mu * mu;
    float inv = rsqrtf(var + 1e-5f);
    float a = g[l * DIM + d] * inv;
    ac[d] = a;
    ac[DIM + d] = b[l * DIM + d] - mu * a;
}

// ---- pooled[g] = mean_i(relu(z[i]*a+c)) over sorted segment [start[g], start[g+1]) ----
template <typename HT>
__global__ __launch_bounds__(256) void pool_seg(const HT* __restrict__ z,
                                                const float* __restrict__ acv,
                                                const int* __restrict__ start,
                                                float* __restrict__ pooled) {
    int g = blockIdx.x, ch = threadIdx.x;
    int r0 = start[g], r1 = start[g + 1];
    float a = acv[ch], c = acv[DIM + ch];
    float s = 0.f;
    for (int i = r0; i < r1; ++i)
        s += fmaxf(loadH(z, (size_t)i * DIM + ch) * a + c, 0.f);
    float n = (float)(r1 - r0);
    pooled[(size_t)g * DIM + ch] = s / fmaxf(n, 1.f);
}

// ---- out = softplus(pooled @ Wo1 + bo1) @ Wo2 + bo2 (pooled pre-averaged), fp32 out ----
__global__ __launch_bounds__(128) void head_mlp(const float* __restrict__ pooled,
                                                const float* __restrict__ Wo1,
                                                const float* __restrict__ bo1,
                                                const float* __restrict__ Wo2,
                                                const float* __restrict__ bo2,
                                                float* __restrict__ out) {
    __shared__ float p[DIM];
    __shared__ float r0[128], r1[128];
    int g = blockIdx.x, j = threadIdx.x;
    for (int k = j; k < DIM; k += 128) p[k] = pooled[(size_t)g * DIM + k];
    __syncthreads();
    float acc = bo1[j];
    for (int k = 0; k < DIM; ++k) acc += p[k] * Wo1[k * 128 + j];
    float sp = (acc > 20.f) ? acc : log1pf(expf(acc));
    r0[j] = sp * Wo2[j * 2 + 0];
    r1[j] = sp * Wo2[j * 2 + 1];
    __syncthreads();
    for (int s = 64; s > 0; s >>= 1) {
        if (j < s) { r0[j] += r0[j + s]; r1[j] += r1[j + s]; }
        __syncthreads();
    }
    if (j == 0) {
        out[g * 2 + 0] = r0[0] + bo2[0];
        out[g * 2 + 1] = r1[0] + bo2[1];
    }
}

template <typename HT>
static void pipeline(void* const* d_in, float* out, char* ws, hipStream_t stream) {
    const int* x     = (const int*)d_in[0];
    const int* ei    = (const int*)d_in[1];
    const int* ea    = (const int*)d_in[2];
    const int* batch = (const int*)d_in[3];
    const float* xe1 = (const float*)d_in[4];
    const float* xe2 = (const float*)d_in[5];
    const float* ee1 = (const float*)d_in[6];
    const float* ee2 = (const float*)d_in[7];
    const float* W1  = (const float*)d_in[8];
    const float* b1  = (const float*)d_in[9];
    const float* W2  = (const float*)d_in[10];
    const float* b2  = (const float*)d_in[11];
    const float* bng = (const float*)d_in[12];
    const float* bnb = (const float*)d_in[13];
    const float* Wo1 = (const float*)d_in[14];
    const float* bo1 = (const float*)d_in[15];
    const float* Wo2 = (const float*)d_in[16];
    const float* bo2 = (const float*)d_in[17];

    size_t off = 0;
    auto alloc = [&](size_t bytes) { void* p = ws + off; off += (bytes + 255) & ~255ull; return p; };
    HT* z               = (HT*)alloc((size_t)NNODES * DIM * sizeof(HT));
    unsigned short* agg = (unsigned short*)alloc((size_t)NNODES * DIM * 2);
    unsigned short* Wt1 = (unsigned short*)alloc((size_t)NLAYERS * DIM * 2 * DIM * 2);
    unsigned short* Wt2 = (unsigned short*)alloc((size_t)NLAYERS * DIM * 2 * DIM * 2);
    float* etab         = (float*)alloc((size_t)NLAYERS * 15 * DIM * 4);
    float* stats        = (float*)alloc(2 * DIM * 4);
    float* ac           = (float*)alloc(2 * DIM * 4);
    float* pooled       = (float*)alloc((size_t)NB * DIM * 4);
    int* gstart         = (int*)alloc((size_t)(NB + 1) * 4);
    int* rowptr         = (int*)alloc((size_t)(NNODES + 1) * 4);
    int* deg            = (int*)alloc((size_t)NNODES * 4);     // also cursor
    int* esrc           = (int*)alloc((size_t)NEDGES * 4);
    int* eattr          = (int*)alloc((size_t)NEDGES * 4);
    int* bsum           = (int*)alloc((size_t)NSB * 4);

    const int WTOT = DIM * 2 * DIM;  // 131072

    // one-time prep
    transpose_w<<<dim3((WTOT + 255) / 256, NLAYERS), 256, 0, stream>>>(W1, Wt1, DIM, 2 * DIM);
    transpose_w<<<dim3((WTOT + 255) / 256, NLAYERS), 256, 0, stream>>>(W2, Wt2, 2 * DIM, DIM);
    build_etab<<<dim3(15, NLAYERS), DIM, 0, stream>>>(ee1, ee2, etab);
    node_init<HT><<<NNODES, DIM, 0, stream>>>(x, xe1, xe2, z);

    // CSR + segment build
    zero_i32<<<(NNODES + 255) / 256, 256, 0, stream>>>(deg, NNODES);
    csr_hist<<<(NEDGES + 255) / 256, 256, 0, stream>>>(ei, deg);
    scan_blk<<<NSB, 1024, 0, stream>>>(deg, rowptr, bsum);
    scan_partials<<<1, 64, 0, stream>>>(bsum);
    scan_add<<<NSB, 1024, 0, stream>>>(rowptr, bsum);
    zero_i32<<<(NNODES + 255) / 256, 256, 0, stream>>>(deg, NNODES);
    csr_fill<<<(NEDGES + 255) / 256, 256, 0, stream>>>(ei, ea, rowptr, deg, esrc, eattr);
    seg_starts<<<(NB + 1 + 255) / 256, 256, 0, stream>>>(batch, gstart);

    for (int l = 0; l < NLAYERS; ++l) {
        gather_csr<HT><<<NNODES / 4, 256, 0, stream>>>(z, ac, etab + (size_t)l * 15 * DIM,
                                                       rowptr, esrc, eattr, agg, l > 0 ? 1 : 0);
        zero_f32<<<2, 256, 0, stream>>>(stats, 2 * DIM);
        mlp64<HT><<<(NNODES + 63) / 64, 512, 0, stream>>>(agg, Wt1 + (size_t)l * WTOT, b1 + l * 2 * DIM,
                                                          Wt2 + (size_t)l * WTOT, b2 + l * DIM, z, stats);
        bn_finalize<<<1, DIM, 0, stream>>>(stats, bng, bnb, ac, l);
    }

    pool_seg<HT><<<NB, DIM, 0, stream>>>(z, ac, gstart, pooled);
    head_mlp<<<NB, 128, 0, stream>>>(pooled, Wo1, bo1, Wo2, bo2, out);
}

extern "C" void kernel_launch(void* const* d_in, const int* in_sizes, int n_in,
                              void* d_out, int out_size, void* d_ws, size_t ws_size,
                              hipStream_t stream) {
    (void)in_sizes; (void)n_in; (void)out_size;
    // layout A (z fp32): ~161 MB ; layout B (z bf16): ~110 MB
    const size_t NEED_A = 161500000ull;
    const size_t NEED_B = 110500000ull;
    if (ws_size >= NEED_A)
        pipeline<float>(d_in, (float*)d_out, (char*)d_ws, stream);
    else if (ws_size >= NEED_B)
        pipeline<unsigned short>(d_in, (float*)d_out, (char*)d_ws, stream);
    // else: insufficient scratch — launch nothing (visible absmax failure, no fault)
}